// Round 6
// baseline (2021.954 us; speedup 1.0000x reference)
//
#include <hip/hip_runtime.h>
#include <hip/hip_fp16.h>

#define B_   64
#define NB   128
#define E_   1024
#define DH   300
#define G3   900
#define OUTD 1924
#define SLICES 4
#define PK_STRIDE 1800
#define MSG_U64 80   // per (b,i): u64 data [19s,19s+19) per slice s (s=3 uses 18) + tags 76..79

typedef _Float16 h2raw __attribute__((ext_vector_type(2)));

__device__ __forceinline__ float dot2f(unsigned int m2, unsigned int w, float acc) {
    h2raw a, b;
    __builtin_memcpy(&a, &m2, 4);
    __builtin_memcpy(&b, &w, 4);
    return __builtin_amdgcn_fdot2(a, b, acc, false);
}

__device__ __forceinline__ unsigned int packh2(float x, float y) {
    __half2 h;
    h.x = __float2half_rn(x);
    h.y = __float2half_rn(y);
    unsigned int u;
    __builtin_memcpy(&u, &h, 4);
    return u;
}

__device__ __forceinline__ float sigmoidf_(float x) { return 1.f / (1.f + __expf(-x)); }
__device__ __forceinline__ float tanh_fast(float x) { return 1.f - 2.f / (__expf(2.f * x) + 1.f); }

// ---------------- copy features into output tail ----------------
__global__ __launch_bounds__(256)
void copy_feat(const float* __restrict__ f, float* __restrict__ out) {
    const long id = (long)blockIdx.x * 256 + threadIdx.x;
    const long r = id >> 8;
    const int  c = (int)(id & 255);
    const float4 v = ((const float4*)(f + r * E_))[c];
    ((float4*)(out + r * OUTD + 3 * DH))[c] = v;
}

// ---------------- pack recurrent weights -> PK2[l][kp(150)][R(1800)] f16-pairs ----------------
__global__ __launch_bounds__(256)
void pack2(const float* __restrict__ gc_whh, const float* __restrict__ gp_wih,
           unsigned int* __restrict__ dst) {
    const int id = blockIdx.x * 256 + threadIdx.x;
    if (id >= 2 * 150 * PK_STRIDE) return;
    const int l   = id / (150 * PK_STRIDE);
    const int rem = id % (150 * PK_STRIDE);
    const int kp  = rem / PK_STRIDE;
    const int R   = rem % PK_STRIDE;
    const int mat = R / G3;
    const int o   = R % G3;
    const float* W = (mat ? gp_wih : gc_whh) + (long)l * G3 * DH;
    const float2 v = *(const float2*)(W + (long)o * DH + 2 * kp);
    dst[id] = packh2(v.x, v.y);
}

// ---------------- fp32 tiled GEMM ----------------
template<int BLAYOUT>
__global__ __launch_bounds__(256)
void gemm_bias(const float* __restrict__ A, int lda,
               const float* __restrict__ Bm, int ldb,
               const float* __restrict__ bias,
               float* __restrict__ C, int ldc,
               int M, int Nn, int K, int do_relu)
{
    __shared__ float As[16][64];
    __shared__ float Bs[16][64];
    const int tid = threadIdx.x;
    const int m0 = blockIdx.y * 64;
    const int n0 = blockIdx.x * 64;
    const int tx = tid & 15, ty = tid >> 4;
    const int ar = tid >> 2, ak = (tid & 3) << 2;
    const int bk0 = tid >> 4, bn0 = (tid & 15) << 2;
    const int bn1 = tid >> 2, bk1 = (tid & 3) << 2;

    float acc[4][4] = {{0.f}};

    for (int k0 = 0; k0 < K; k0 += 16) {
        {
            const int gr = m0 + ar;
            const int gk = k0 + ak;
            const float* ap = A + (long)gr * lda + gk;
            float v0, v1, v2, v3;
            if (gk + 3 < K) { float4 v = *(const float4*)ap; v0 = v.x; v1 = v.y; v2 = v.z; v3 = v.w; }
            else {
                v0 = (gk + 0 < K) ? ap[0] : 0.f;
                v1 = (gk + 1 < K) ? ap[1] : 0.f;
                v2 = (gk + 2 < K) ? ap[2] : 0.f;
                v3 = (gk + 3 < K) ? ap[3] : 0.f;
            }
            As[ak + 0][ar] = v0; As[ak + 1][ar] = v1; As[ak + 2][ar] = v2; As[ak + 3][ar] = v3;
        }
        if (BLAYOUT == 0) {
            const int gk = k0 + bk0;
            const int gn = n0 + bn0;
            const float* bp = Bm + (long)gk * ldb + gn;
            float4 v;
            if (gk < K && gn + 3 < Nn) v = *(const float4*)bp;
            else {
                v.x = (gk < K && gn + 0 < Nn) ? bp[0] : 0.f;
                v.y = (gk < K && gn + 1 < Nn) ? bp[1] : 0.f;
                v.z = (gk < K && gn + 2 < Nn) ? bp[2] : 0.f;
                v.w = (gk < K && gn + 3 < Nn) ? bp[3] : 0.f;
            }
            *(float4*)&Bs[bk0][bn0] = v;
        } else {
            const int gn = n0 + bn1;
            const int gk = k0 + bk1;
            const float* bp = Bm + (long)gn * ldb + gk;
            float v0, v1, v2, v3;
            if (gn < Nn && gk + 3 < K) { float4 v = *(const float4*)bp; v0 = v.x; v1 = v.y; v2 = v.z; v3 = v.w; }
            else {
                v0 = (gn < Nn && gk + 0 < K) ? bp[0] : 0.f;
                v1 = (gn < Nn && gk + 1 < K) ? bp[1] : 0.f;
                v2 = (gn < Nn && gk + 2 < K) ? bp[2] : 0.f;
                v3 = (gn < Nn && gk + 3 < K) ? bp[3] : 0.f;
            }
            Bs[bk1 + 0][bn1] = v0; Bs[bk1 + 1][bn1] = v1; Bs[bk1 + 2][bn1] = v2; Bs[bk1 + 3][bn1] = v3;
        }
        __syncthreads();
        #pragma unroll
        for (int kk = 0; kk < 16; ++kk) {
            const float4 a4 = *(const float4*)&As[kk][ty << 2];
            const float4 b4 = *(const float4*)&Bs[kk][tx << 2];
            const float a[4] = {a4.x, a4.y, a4.z, a4.w};
            const float b[4] = {b4.x, b4.y, b4.z, b4.w};
            #pragma unroll
            for (int ii = 0; ii < 4; ++ii)
                #pragma unroll
                for (int jj = 0; jj < 4; ++jj)
                    acc[ii][jj] += a[ii] * b[jj];
        }
        __syncthreads();
    }
    const int gn0 = n0 + (tx << 2);
    #pragma unroll
    for (int ii = 0; ii < 4; ++ii) {
        const int gm = m0 + (ty << 2) + ii;
        if (gm >= M) continue;
        if (gn0 + 3 < Nn) {
            const float4 bb = *(const float4*)&bias[gn0];
            float4 o;
            o.x = acc[ii][0] + bb.x; o.y = acc[ii][1] + bb.y;
            o.z = acc[ii][2] + bb.z; o.w = acc[ii][3] + bb.w;
            if (do_relu) { o.x = fmaxf(o.x, 0.f); o.y = fmaxf(o.y, 0.f); o.z = fmaxf(o.z, 0.f); o.w = fmaxf(o.w, 0.f); }
            *(float4*)&C[(long)gm * ldc + gn0] = o;
        } else if (gn0 < Nn) {
            for (int jj = 0; jj < 4; ++jj) {
                const int gn = gn0 + jj;
                if (gn < Nn) {
                    float v = acc[ii][jj] + bias[gn];
                    if (do_relu) v = fmaxf(v, 0.f);
                    C[(long)gm * ldc + gn] = v;
                }
            }
        }
    }
}

// ---------------- DAG scan v6: v5 structure, divergent-shfl bug fixed ----------------
// Softmax identity: alpha_j = (x_i.wq + bg) + beta_j; the x/bg term is constant over j and
// cancels in softmax => weights depend only on beta_j and the adjacency mask.
__global__ __launch_bounds__(512, 2)
void scan6(float* __restrict__ out,
           const float* __restrict__ GIC,
           const float* __restrict__ GHP,
           const unsigned int* __restrict__ PK2L,
           const float* __restrict__ cbhh,
           const float* __restrict__ pbih,
           const int* __restrict__ adj,
           const float* __restrict__ wk,
           unsigned long long* __restrict__ TBL,
           int l)
{
    extern __shared__ unsigned int histp[];   // [128][152] f16-pairs (pair index = global dim/2)
    __shared__ float betas[NB];
    __shared__ float Mlds[DH];
    __shared__ __align__(16) unsigned int M2[152];
    __shared__ float gmv[456];
    __shared__ unsigned int zpair[8];
    __shared__ float zbeta;
    __shared__ unsigned long long amask[2][2];

    const int tid = threadIdx.x;
    const int lane = tid & 63;
    const int wid = tid >> 6;
    const int b = blockIdx.x & 63;
    const int k = blockIdx.x >> 6;
    const int swk = (k == 3) ? 72 : 76;       // slice dims
    const int npairs = swk >> 1;              // 38 / 36
    const int nwords = (npairs + 1) >> 1;     // 19 / 18

    float* outb = out + (long)b * NB * OUTD;
    const float* xcol = outb + l * DH;
    float* ycol = outb + (l + 1) * DH;
    const float* gicb = GIC + (long)b * NB * G3;
    const float* ghpb = GHP + (long)b * NB * G3;
    const int* adjb = adj + b * NB * NB;
    unsigned long long* tbu64 = TBL + (long)b * NB * MSG_U64;

    if (tid < 152) M2[tid] = 0u;
    if (tid < DH) Mlds[tid] = 0.f;
    if (tid == 0) zbeta = 0.f;

    // per-dim loop invariants (valid for tid < swk)
    const int D = 76 * k + ((tid < swk) ? tid : 0);
    const float cb0 = cbhh[D], cb1 = cbhh[DH + D], cb2 = cbhh[2 * DH + D];
    const float pb0 = pbih[D], pb1 = pbih[DH + D], pb2 = pbih[2 * DH + D];
    const float wkD = wk[D];

    // this slice's weight rows into registers
    const int ROWS = 6 * swk;
    int R;
    {
        const int t = (tid < ROWS) ? tid : 0;
        const int d = t % swk;
        const int r = t / swk;                // 0..5 = (mat, gate)
        R = (r / 3) * G3 + (r % 3) * DH + 76 * k + d;
    }
    unsigned int w[152];
    #pragma unroll
    for (int j = 0; j < 150; ++j) w[j] = PK2L[j * PK_STRIDE + R];
    w[150] = 0u; w[151] = 0u;

    __syncthreads();

    unsigned int pairu32 = 0;   // this lane's f16 pair of the row produced last iteration
    float bown = 0.f;           // wave0: this slice's beta partial of last row

    for (int i = 0; i < NB; ++i) {
        // ---- prefetch gate inputs for row i (fire early; consumed at the end) ----
        float gi0 = 0, gi1 = 0, gi2 = 0, gp0 = 0, gp1 = 0, gp2 = 0, xi = 0;
        if (tid < swk) {
            const float* gic = gicb + (long)i * G3;
            const float* ghp = ghpb + (long)i * G3;
            gi0 = gic[D]; gi1 = gic[DH + D]; gi2 = gic[2 * DH + D];
            gp0 = ghp[D]; gp1 = ghp[DH + D]; gp2 = ghp[2 * DH + D];
            xi = xcol[(long)i * OUTD + D];
        }

        float M1 = -3.0e38f, S = 0.f, V0 = 0.f, V1 = 0.f;   // V-thread online softmax state
        const bool is_v = (tid >= 64) && (tid < 214);
        const int vt = tid - 64;

        if (i > 0) {
            __syncthreads();   // B6: row i-1 gates done; zpair/zbeta written

            if (wid == 0) {
                // ======== producer: assemble + ship row i-1 ========
                unsigned long long* trow = tbu64 + (long)(i - 1) * MSG_U64;
                const float bfull = bown + zbeta;

                // FULL-WAVE shuffles (sources must be active: no divergence here)
                const unsigned int sh_hist = __shfl(pairu32, (2 * lane) & 63);      // pair 'lane'
                const unsigned int sh_lo   = __shfl(pairu32, (4 * lane) & 63);      // pair 2*lane
                const unsigned int sh_hi   = __shfl(pairu32, (4 * lane + 2) & 63);  // pair 2*lane+1

                // own slice history -> LDS
                if (lane < npairs) {
                    const unsigned int val = (lane < 32) ? sh_hist : zpair[lane - 32];
                    histp[(i - 1) * 152 + 38 * k + lane] = val;
                }
                // mailbox data words
                if (lane < nwords) {
                    unsigned int lo, hi;
                    if (lane < 16) {
                        lo = sh_lo;
                        hi = sh_hi;
                    } else {
                        lo = zpair[2 * (lane - 16)];
                        hi = zpair[2 * (lane - 16) + 1];
                    }
                    const unsigned long long d = ((unsigned long long)hi << 32) | lo;
                    __hip_atomic_store(&trow[19 * k + lane], d,
                                       __ATOMIC_RELAXED, __HIP_MEMORY_SCOPE_AGENT);
                }
                // wave-local drain of the data stores, then tag
                asm volatile("s_waitcnt vmcnt(0)" ::: "memory");
                if (lane == 0) {
                    unsigned int bbits;
                    __builtin_memcpy(&bbits, &bfull, 4);
                    const unsigned long long pkt =
                        ((unsigned long long)bbits << 32) | (unsigned int)i;
                    __hip_atomic_store(&trow[76 + k], pkt,
                                       __ATOMIC_RELAXED, __HIP_MEMORY_SCOPE_AGENT);
                }

                // ======== consumer: poll 3 remote slices of row i-1 ========
                const bool act = (lane < SLICES) && (lane != k);
                unsigned long long tv = 0;
                while (true) {
                    if (act && (unsigned int)tv != (unsigned int)i)
                        tv = __hip_atomic_load(&trow[76 + lane],
                                               __ATOMIC_RELAXED, __HIP_MEMORY_SCOPE_AGENT);
                    if (__all(!act || (unsigned int)tv == (unsigned int)i)) break;
                }
                float bp = 0.f;
                if (lane < SLICES) {
                    if (lane == k) bp = bfull;
                    else {
                        const unsigned int hib = (unsigned int)(tv >> 32);
                        __builtin_memcpy(&bp, &hib, 4);
                    }
                }
                bp += __shfl_xor(bp, 1);
                bp += __shfl_xor(bp, 2);
                if (lane == 0) betas[i - 1] = bp;

                // remote data -> LDS history
                if (lane < 57) {
                    const int s = (k + 1 + lane / 19) & 3;
                    const int ww = lane % 19;
                    const int nw = (s == 3) ? 18 : 19;
                    if (ww < nw) {
                        const unsigned long long d =
                            __hip_atomic_load(&trow[19 * s + ww],
                                              __ATOMIC_RELAXED, __HIP_MEMORY_SCOPE_AGENT);
                        histp[(i - 1) * 152 + 38 * s + 2 * ww] = (unsigned int)d;
                        histp[(i - 1) * 152 + 38 * s + 2 * ww + 1] = (unsigned int)(d >> 32);
                    }
                }
            } else if (is_v) {
                // ======== online masked softmax partials over j <= i-2 (overlaps poll) ========
                const unsigned long long am0 = amask[i & 1][0];
                const unsigned long long am1 = amask[i & 1][1];
                const int e0 = (i - 1 < 64) ? (i - 1) : 64;
                for (int j = 0; j < e0; ++j) {
                    if ((am0 >> j) & 1) {
                        const float bj = betas[j];
                        float e;
                        if (bj > M1) {
                            const float f = __expf(M1 - bj);
                            S *= f; V0 *= f; V1 *= f; M1 = bj; e = 1.f;
                        } else e = __expf(bj - M1);
                        const unsigned int u = histp[j * 152 + vt];
                        __half2 h; __builtin_memcpy(&h, &u, 4);
                        S += e;
                        V0 = fmaf(e, __half2float(h.x), V0);
                        V1 = fmaf(e, __half2float(h.y), V1);
                    }
                }
                for (int j = 64; j < i - 1; ++j) {
                    if ((am1 >> (j - 64)) & 1) {
                        const float bj = betas[j];
                        float e;
                        if (bj > M1) {
                            const float f = __expf(M1 - bj);
                            S *= f; V0 *= f; V1 *= f; M1 = bj; e = 1.f;
                        } else e = __expf(bj - M1);
                        const unsigned int u = histp[j * 152 + vt];
                        __half2 h; __builtin_memcpy(&h, &u, 4);
                        S += e;
                        V0 = fmaf(e, __half2float(h.x), V0);
                        V1 = fmaf(e, __half2float(h.y), V1);
                    }
                }
            } else if (wid == 4 && i + 1 < NB) {
                // adjacency mask for row i+1 -> slot (i+1)&1
                const int a0 = adjb[(i + 1) * NB + lane];
                const int a1 = adjb[(i + 1) * NB + 64 + lane];
                const unsigned long long b0 = __ballot(a0 != 0);
                const unsigned long long b1 = __ballot(a1 != 0);
                if (lane == 0) {
                    amask[(i + 1) & 1][0] = b0;
                    amask[(i + 1) & 1][1] = b1;
                }
            }
            __syncthreads();   // B1: betas[i-1] + history row i-1 + V partials ready

            // ---- late term j = i-1 (always valid: adj[i][i-1]==1), finalize M ----
            if (is_v) {
                const float bj = betas[i - 1];
                float e;
                if (bj > M1) {
                    const float f = __expf(M1 - bj);
                    S *= f; V0 *= f; V1 *= f; e = 1.f;
                } else e = __expf(bj - M1);
                const unsigned int u = histp[(i - 1) * 152 + vt];
                __half2 h; __builtin_memcpy(&h, &u, 4);
                S += e;
                V0 = fmaf(e, __half2float(h.x), V0);
                V1 = fmaf(e, __half2float(h.y), V1);
                const float inv = 1.f / S;
                const float m0 = V0 * inv, m1 = V1 * inv;
                Mlds[2 * vt] = m0;
                Mlds[2 * vt + 1] = m1;
                M2[vt] = packh2(m0, m1);
            }
            __syncthreads();   // B4: M ready
        } else {
            if (wid == 4) {
                const int a0 = adjb[NB + lane];
                const int a1 = adjb[NB + 64 + lane];
                const unsigned long long b0 = __ballot(a0 != 0);
                const unsigned long long b1 = __ballot(a1 != 0);
                if (lane == 0) { amask[1][0] = b0; amask[1][1] = b1; }
            }
            // M2/Mlds zeroed before the init barrier; no extra barrier needed
        }

        // ---- matvec from register weights ----
        if (tid < ROWS) {
            float a0 = 0.f, a1 = 0.f;
            #pragma unroll
            for (int j4 = 0; j4 < 152; j4 += 4) {
                const uint4 m4 = *(const uint4*)&M2[j4];
                a0 = dot2f(m4.x, w[j4 + 0], a0);
                a1 = dot2f(m4.y, w[j4 + 1], a1);
                a0 = dot2f(m4.z, w[j4 + 2], a0);
                a1 = dot2f(m4.w, w[j4 + 3], a1);
            }
            gmv[tid] = a0 + a1;
        }
        __syncthreads();   // B5: gmv ready

        // ---- gates for this slice's dims ----
        float rowv = 0.f;
        if (tid < swk) {
            const float Mi = Mlds[D];
            const float hc0 = gmv[0 * swk + tid] + cb0;
            const float hc1 = gmv[1 * swk + tid] + cb1;
            const float hc2 = gmv[2 * swk + tid] + cb2;
            const float rc = sigmoidf_(gi0 + hc0);
            const float zc = sigmoidf_(gi1 + hc1);
            const float nc = tanh_fast(gi2 + rc * hc2);
            const float Cc = (1.f - zc) * nc + zc * Mi;
            const float ip0 = gmv[3 * swk + tid] + pb0;
            const float ip1 = gmv[4 * swk + tid] + pb1;
            const float ip2 = gmv[5 * swk + tid] + pb2;
            const float rp = sigmoidf_(ip0 + gp0);
            const float zp = sigmoidf_(ip1 + gp1);
            const float np = tanh_fast(ip2 + rp * gp2);
            const float Pp = (1.f - zp) * np + zp * xi;
            rowv = Cc + Pp;
            ycol[(long)i * OUTD + D] = rowv;   // off critical path
        }
        {
            const float pr = __shfl_xor(rowv, 1);   // unconditional: all lanes active
            pairu32 = packh2(rowv, pr);             // meaningful in even lanes
        }
        float bv = (tid < swk) ? rowv * wkD : 0.f;
        if (wid == 0) {
            #pragma unroll
            for (int off = 32; off; off >>= 1) bv += __shfl_xor(bv, off);
            bown = bv;                          // dims 0..63 partial (all lanes)
        } else if (wid == 1) {
            if (tid < swk && !(lane & 1)) zpair[lane >> 1] = pairu32;
            #pragma unroll
            for (int off = 32; off; off >>= 1) bv += __shfl_xor(bv, off);
            if (lane == 0) zbeta = bv;          // dims 64..swk-1 partial
        }
    }
}

extern "C" void kernel_launch(void* const* d_in, const int* in_sizes, int n_in,
                              void* d_out, int out_size, void* d_ws, size_t ws_size,
                              hipStream_t stream) {
    (void)in_sizes; (void)n_in; (void)out_size; (void)ws_size;
    const float* features = (const float*)d_in[0];
    const float* fc1_w    = (const float*)d_in[1];
    const float* fc1_b    = (const float*)d_in[2];
    const float* gat_w    = (const float*)d_in[3];
    const float* gc_wih   = (const float*)d_in[5];
    const float* gc_whh   = (const float*)d_in[6];
    const float* gc_bih   = (const float*)d_in[7];
    const float* gc_bhh   = (const float*)d_in[8];
    const float* gp_wih   = (const float*)d_in[9];
    const float* gp_whh   = (const float*)d_in[10];
    const float* gp_bih   = (const float*)d_in[11];
    const float* gp_bhh   = (const float*)d_in[12];
    const int*   adj      = (const int*)d_in[13];
    float* out = (float*)d_out;

    unsigned long long* TB = (unsigned long long*)d_ws;        // 2 * 64*128*80 u64
    float* GIC = (float*)(TB + 2L * B_ * NB * MSG_U64);        // 64*128*900
    float* GHP = GIC + (long)B_ * NB * G3;                     // 64*128*900
    unsigned int* PK2 = (unsigned int*)(GHP + (long)B_ * NB * G3);  // 2*150*1800

    hipFuncSetAttribute(reinterpret_cast<const void*>(scan6),
                        hipFuncAttributeMaxDynamicSharedMemorySize, 80000);
    hipMemsetAsync(TB, 0, 2L * B_ * NB * MSG_U64 * sizeof(unsigned long long), stream);

    copy_feat<<<dim3((B_ * NB * E_) / 1024), 256, 0, stream>>>(features, out);
    pack2<<<dim3((2 * 150 * PK_STRIDE + 255) / 256), 256, 0, stream>>>(gc_whh, gp_wih, PK2);

    gemm_bias<0><<<dim3(5, 128), 256, 0, stream>>>(
        features, E_, fc1_w, DH, fc1_b, out, OUTD, B_ * NB, DH, E_, 1);

    for (int l = 0; l < 2; ++l) {
        const float* Hl = out + l * DH;
        gemm_bias<1><<<dim3(15, 128), 256, 0, stream>>>(
            Hl, OUTD, gc_wih + (long)l * G3 * DH, DH, gc_bih + l * G3, GIC, G3, B_ * NB, G3, DH, 0);
        gemm_bias<1><<<dim3(15, 128), 256, 0, stream>>>(
            Hl, OUTD, gp_whh + (long)l * G3 * DH, DH, gp_bhh + l * G3, GHP, G3, B_ * NB, G3, DH, 0);
        scan6<<<dim3(SLICES * B_), 512, 77824, stream>>>(
            out, GIC, GHP, PK2 + (long)l * 150 * PK_STRIDE,
            gc_bhh + l * G3, gp_bih + l * G3, adj,
            gat_w + l * 2 * DH + DH,
            TB + (long)l * B_ * NB * MSG_U64, l);
    }
}

// Round 7
// 1489.140 us; speedup vs baseline: 1.3578x; 1.3578x over previous
//
#include <hip/hip_runtime.h>
#include <hip/hip_fp16.h>

#define B_   64
#define NB   128
#define E_   1024
#define DH   300
#define G3   900
#define OUTD 1924
#define SLICES 4
#define PK_STRIDE 1800
#define MSG_U64 80   // per (b,i): 75 u64 data (150 f16-pair words) + pad + 4 tag u64

typedef _Float16 h2raw __attribute__((ext_vector_type(2)));

__device__ __forceinline__ float dot2f(unsigned int m2, unsigned int w, float acc) {
    h2raw a, b;
    __builtin_memcpy(&a, &m2, 4);
    __builtin_memcpy(&b, &w, 4);
    return __builtin_amdgcn_fdot2(a, b, acc, false);
}

__device__ __forceinline__ unsigned int packh2(float x, float y) {
    __half2 h;
    h.x = __float2half_rn(x);
    h.y = __float2half_rn(y);
    unsigned int u;
    __builtin_memcpy(&u, &h, 4);
    return u;
}

__device__ __forceinline__ float sigmoidf_(float x) { return 1.f / (1.f + __expf(-x)); }
__device__ __forceinline__ float tanh_fast(float x) { return 1.f - 2.f / (__expf(2.f * x) + 1.f); }

// ---------------- copy features into output tail ----------------
__global__ __launch_bounds__(256)
void copy_feat(const float* __restrict__ f, float* __restrict__ out) {
    const long id = (long)blockIdx.x * 256 + threadIdx.x;
    const long r = id >> 8;
    const int  c = (int)(id & 255);
    const float4 v = ((const float4*)(f + r * E_))[c];
    ((float4*)(out + r * OUTD + 3 * DH))[c] = v;
}

// ---------------- pack recurrent weights -> PK2[l][kp(150)][R(1800)] f16-pairs ----------------
__global__ __launch_bounds__(256)
void pack2(const float* __restrict__ gc_whh, const float* __restrict__ gp_wih,
           unsigned int* __restrict__ dst) {
    const int id = blockIdx.x * 256 + threadIdx.x;
    if (id >= 2 * 150 * PK_STRIDE) return;
    const int l   = id / (150 * PK_STRIDE);
    const int rem = id % (150 * PK_STRIDE);
    const int kp  = rem / PK_STRIDE;
    const int R   = rem % PK_STRIDE;
    const int mat = R / G3;
    const int o   = R % G3;
    const float* W = (mat ? gp_wih : gc_whh) + (long)l * G3 * DH;
    const float2 v = *(const float2*)(W + (long)o * DH + 2 * kp);
    dst[id] = packh2(v.x, v.y);
}

// ---------------- GEMM input packing to f16 pairs ----------------
// A dense: src [8192][1024] f32 -> dst [8192][512] u32
__global__ __launch_bounds__(256)
void pack_af(const float* __restrict__ src, unsigned int* __restrict__ dst) {
    const long id = (long)blockIdx.x * 256 + threadIdx.x;   // 8192*512
    const long r = id >> 9;
    const int kp = (int)(id & 511);
    const float2 v = *(const float2*)(src + r * E_ + 2 * kp);
    dst[id] = packh2(v.x, v.y);
}

// A strided (Hl in out): src row stride 1924, 300 wide -> dst [8192][160] u32 (kp>=150 zero)
__global__ __launch_bounds__(256)
void pack_ah(const float* __restrict__ src, unsigned int* __restrict__ dst) {
    const long id = (long)blockIdx.x * 256 + threadIdx.x;   // 8192*160
    const long r = id / 160;
    const int kp = (int)(id % 160);
    unsigned int u = 0u;
    if (kp < 150) {
        const float2 v = *(const float2*)(src + r * OUTD + 2 * kp);
        u = packh2(v.x, v.y);
    }
    dst[id] = u;
}

// B from k-major weight: fc1_w [1024][300] -> dst [320][512] u32 (n>=300 zero)
__global__ __launch_bounds__(256)
void pack_bf(const float* __restrict__ W, unsigned int* __restrict__ dst) {
    const int id = blockIdx.x * 256 + threadIdx.x;          // 320*512
    const int n = id >> 9;
    const int kp = id & 511;
    unsigned int u = 0u;
    if (n < DH) u = packh2(W[(2 * kp) * DH + n], W[(2 * kp + 1) * DH + n]);
    dst[id] = u;
}

// B from n-major weight: W [900][300] -> dst [960][160] u32 (pads zero)
__global__ __launch_bounds__(256)
void pack_bw(const float* __restrict__ W, unsigned int* __restrict__ dst) {
    const int id = blockIdx.x * 256 + threadIdx.x;          // 960*160
    const int n = id / 160;
    const int kp = id % 160;
    unsigned int u = 0u;
    if (n < G3 && kp < 150) {
        const float2 v = *(const float2*)(W + (long)n * DH + 2 * kp);
        u = packh2(v.x, v.y);
    }
    dst[id] = u;
}

// ---------------- f16-dot2 GEMM: C[128xBM tile] = A*B^T(+bias) ----------------
// APK: [M][ldap] u32 pairs; BPK: [Npad][ldbp] u32 pairs (rows padded). Tile 128x64.
template<int RELU>
__global__ __launch_bounds__(256)
void gemm_h16(const unsigned int* __restrict__ APK, int ldap,
              const unsigned int* __restrict__ BPK, int ldbp,
              const float* __restrict__ bias,
              float* __restrict__ C, int ldc,
              int N, int KP)
{
    __shared__ __align__(16) unsigned int As[16][132];
    __shared__ __align__(16) unsigned int Bs[16][68];
    const int tid = threadIdx.x;
    const int m0 = blockIdx.y * 128;
    const int n0 = blockIdx.x * 64;
    const int tx = tid & 15, ty = tid >> 4;
    const int am = tid >> 1, ak8 = (tid & 1) * 8;
    const int bn = tid >> 2, bk4 = (tid & 3) * 4;

    float acc[8][4] = {{0.f}};
    const unsigned int* ap = APK + (long)(m0 + am) * ldap + ak8;
    const unsigned int* bp = BPK + (long)(n0 + bn) * ldbp + bk4;

    for (int kp0 = 0; kp0 < KP; kp0 += 16) {
        const uint4 a0 = *(const uint4*)(ap + kp0);
        const uint4 a1 = *(const uint4*)(ap + kp0 + 4);
        const uint4 bq = *(const uint4*)(bp + kp0);
        As[ak8 + 0][am] = a0.x; As[ak8 + 1][am] = a0.y;
        As[ak8 + 2][am] = a0.z; As[ak8 + 3][am] = a0.w;
        As[ak8 + 4][am] = a1.x; As[ak8 + 5][am] = a1.y;
        As[ak8 + 6][am] = a1.z; As[ak8 + 7][am] = a1.w;
        Bs[bk4 + 0][bn] = bq.x; Bs[bk4 + 1][bn] = bq.y;
        Bs[bk4 + 2][bn] = bq.z; Bs[bk4 + 3][bn] = bq.w;
        __syncthreads();
        #pragma unroll
        for (int kp = 0; kp < 16; ++kp) {
            const uint4 aA = *(const uint4*)&As[kp][ty * 8];
            const uint4 aB = *(const uint4*)&As[kp][ty * 8 + 4];
            const uint4 bb = *(const uint4*)&Bs[kp][tx * 4];
            const unsigned int av[8] = {aA.x, aA.y, aA.z, aA.w, aB.x, aB.y, aB.z, aB.w};
            const unsigned int bv[4] = {bb.x, bb.y, bb.z, bb.w};
            #pragma unroll
            for (int ii = 0; ii < 8; ++ii)
                #pragma unroll
                for (int jj = 0; jj < 4; ++jj)
                    acc[ii][jj] = dot2f(av[ii], bv[jj], acc[ii][jj]);
        }
        __syncthreads();
    }

    const int gn0 = n0 + tx * 4;
    #pragma unroll
    for (int ii = 0; ii < 8; ++ii) {
        const int gm = m0 + ty * 8 + ii;
        float* cp = C + (long)gm * ldc + gn0;
        if (gn0 + 3 < N) {
            const float4 bb = *(const float4*)&bias[gn0];
            float4 o;
            o.x = acc[ii][0] + bb.x; o.y = acc[ii][1] + bb.y;
            o.z = acc[ii][2] + bb.z; o.w = acc[ii][3] + bb.w;
            if (RELU) { o.x = fmaxf(o.x, 0.f); o.y = fmaxf(o.y, 0.f); o.z = fmaxf(o.z, 0.f); o.w = fmaxf(o.w, 0.f); }
            *(float4*)cp = o;
        } else if (gn0 < N) {
            for (int jj = 0; jj < 4; ++jj) {
                const int gn = gn0 + jj;
                if (gn < N) {
                    float v = acc[ii][jj] + bias[gn];
                    if (RELU) v = fmaxf(v, 0.f);
                    cp[jj] = v;
                }
            }
        }
    }
}

// ---------------- DAG scan v7 == proven v4 structure, XQ term removed (cancels in softmax) ----------------
__global__ __launch_bounds__(512, 2)
void scan7(float* __restrict__ out,
           const float* __restrict__ GIC,
           const float* __restrict__ GHP,
           const unsigned int* __restrict__ PK2L,
           const float* __restrict__ cbhh,
           const float* __restrict__ pbih,
           const int* __restrict__ adj,
           const float* __restrict__ wk,
           unsigned long long* __restrict__ TBL,
           int l)
{
    extern __shared__ unsigned int histp[];   // [128][152] f16-pairs
    __shared__ float wsm[NB];
    __shared__ float betas[NB];
    __shared__ float Mlds[DH];
    __shared__ __align__(16) unsigned int M2[152];
    __shared__ float gmv[456];
    __shared__ float red[8];

    const int tid = threadIdx.x;
    const int lane = tid & 63;
    const int wid = tid >> 6;
    const int b = blockIdx.x & 63;
    const int k = blockIdx.x >> 6;
    const int swk = (k == 3) ? 72 : 76;

    float* outb = out + (long)b * NB * OUTD;
    const float* xcol = outb + l * DH;
    float* ycol = outb + (l + 1) * DH;
    const float* gicb = GIC + (long)b * NB * G3;
    const float* ghpb = GHP + (long)b * NB * G3;
    const int* adjb = adj + b * NB * NB;
    unsigned long long* tbu64 = TBL + (long)b * NB * MSG_U64;
    unsigned int* tb32 = (unsigned int*)tbu64;

    if (tid < 152) M2[tid] = 0u;

    const int D = 76 * k + ((tid < swk) ? tid : 0);
    const float cb0 = cbhh[D], cb1 = cbhh[DH + D], cb2 = cbhh[2 * DH + D];
    const float pb0 = pbih[D], pb1 = pbih[DH + D], pb2 = pbih[2 * DH + D];
    const float wkD = wk[D];

    const int ROWS = 6 * swk;
    int R;
    {
        const int t = (tid < ROWS) ? tid : 0;
        const int d = t % swk;
        const int r = t / swk;
        R = (r / 3) * G3 + (r % 3) * DH + 76 * k + d;
    }
    unsigned int w[152];
    #pragma unroll
    for (int j = 0; j < 150; ++j) w[j] = PK2L[j * PK_STRIDE + R];
    w[150] = 0u; w[151] = 0u;

    __syncthreads();

    for (int i = 0; i < NB; ++i) {
        // ---- prefetch (overlaps poll) ----
        int adj0 = 0, adj1 = 0;
        if (wid == 0 && i > 0) {
            adj0 = adjb[i * NB + lane];
            adj1 = adjb[i * NB + 64 + lane];
        }
        float gi0 = 0, gi1 = 0, gi2 = 0, gp0 = 0, gp1 = 0, gp2 = 0, xi = 0;
        if (tid < swk) {
            const float* gic = gicb + (long)i * G3;
            const float* ghp = ghpb + (long)i * G3;
            gi0 = gic[D]; gi1 = gic[DH + D]; gi2 = gic[2 * DH + D];
            gp0 = ghp[D]; gp1 = ghp[DH + D]; gp2 = ghp[2 * DH + D];
            xi = xcol[(long)i * OUTD + D];
        }

        if (i > 0) {
            if (wid == 0) {
                const unsigned long long* trow = tbu64 + (long)(i - 1) * MSG_U64;
                const bool act = (lane < SLICES);
                unsigned long long tv = 0;
                while (true) {
                    if (act && (unsigned int)tv != (unsigned int)i)
                        tv = __hip_atomic_load(&trow[76 + lane],
                                               __ATOMIC_RELAXED, __HIP_MEMORY_SCOPE_AGENT);
                    if (__all(!act || (unsigned int)tv == (unsigned int)i)) break;
                }
                float bp = 0.f;
                if (act) {
                    const unsigned int hi = (unsigned int)(tv >> 32);
                    __builtin_memcpy(&bp, &hi, 4);
                }
                bp += __shfl_xor(bp, 1);
                bp += __shfl_xor(bp, 2);
                const float beta_new = __shfl(bp, 0);
                if (lane == 0) betas[i - 1] = beta_new;

                unsigned long long d0 = 0, d1 = 0;
                if (lane < 38) {
                    d0 = __hip_atomic_load(&trow[2 * lane],
                                           __ATOMIC_RELAXED, __HIP_MEMORY_SCOPE_AGENT);
                    d1 = __hip_atomic_load(&trow[2 * lane + 1],
                                           __ATOMIC_RELAXED, __HIP_MEMORY_SCOPE_AGENT);
                }

                // wave0 softmax over j < i (2 j's per lane); base term cancels
                const int j1 = lane + 64;
                const bool v0 = (lane < i) && (adj0 != 0);
                const bool v1 = (j1 < i) && (adj1 != 0);
                const float bb0 = (lane == i - 1) ? beta_new : betas[lane];
                const float bb1 = (j1 == i - 1) ? beta_new : betas[j1 & (NB - 1)];
                float a0 = v0 ? bb0 : -3.0e38f;
                float a1 = v1 ? bb1 : -3.0e38f;
                float mx = fmaxf(a0, a1);
                #pragma unroll
                for (int off = 32; off; off >>= 1) mx = fmaxf(mx, __shfl_xor(mx, off));
                const float e0 = v0 ? __expf(a0 - mx) : 0.f;
                const float e1 = v1 ? __expf(a1 - mx) : 0.f;
                float s = e0 + e1;
                #pragma unroll
                for (int off = 32; off; off >>= 1) s += __shfl_xor(s, off);
                const float inv = 1.f / s;
                wsm[lane] = e0 * inv;
                wsm[j1]   = e1 * inv;

                if (lane < 38) {
                    uint4 q;
                    q.x = (unsigned int)d0; q.y = (unsigned int)(d0 >> 32);
                    q.z = (unsigned int)d1; q.w = (unsigned int)(d1 >> 32);
                    *(uint4*)&histp[(i - 1) * 152 + 4 * lane] = q;
                }
            }
            __syncthreads();   // B1

            if (tid < 150) {
                float m0 = 0.f, m1 = 0.f;
                #pragma unroll 4
                for (int j = 0; j < i; ++j) {
                    const unsigned int u = histp[j * 152 + tid];
                    __half2 h;
                    __builtin_memcpy(&h, &u, 4);
                    const float wj = wsm[j];
                    m0 = fmaf(wj, __half2float(h.x), m0);
                    m1 = fmaf(wj, __half2float(h.y), m1);
                }
                Mlds[2 * tid] = m0;
                Mlds[2 * tid + 1] = m1;
                M2[tid] = packh2(m0, m1);
            }
        } else {
            if (tid < DH) Mlds[tid] = 0.f;
        }
        __syncthreads();   // B4

        if (tid < ROWS) {
            float a0 = 0.f, a1 = 0.f;
            #pragma unroll
            for (int j4 = 0; j4 < 152; j4 += 4) {
                const uint4 m4 = *(const uint4*)&M2[j4];
                a0 = dot2f(m4.x, w[j4 + 0], a0);
                a1 = dot2f(m4.y, w[j4 + 1], a1);
                a0 = dot2f(m4.z, w[j4 + 2], a0);
                a1 = dot2f(m4.w, w[j4 + 3], a1);
            }
            gmv[tid] = a0 + a1;
        }
        __syncthreads();   // B5

        float rowv = 0.f;
        if (tid < swk) {
            const float Mi = Mlds[D];
            const float hc0 = gmv[0 * swk + tid] + cb0;
            const float hc1 = gmv[1 * swk + tid] + cb1;
            const float hc2 = gmv[2 * swk + tid] + cb2;
            const float rc = sigmoidf_(gi0 + hc0);
            const float zc = sigmoidf_(gi1 + hc1);
            const float nc = tanh_fast(gi2 + rc * hc2);
            const float Cc = (1.f - zc) * nc + zc * Mi;
            const float ip0 = gmv[3 * swk + tid] + pb0;
            const float ip1 = gmv[4 * swk + tid] + pb1;
            const float ip2 = gmv[5 * swk + tid] + pb2;
            const float rp = sigmoidf_(ip0 + gp0);
            const float zp = sigmoidf_(ip1 + gp1);
            const float np = tanh_fast(ip2 + rp * gp2);
            const float Pp = (1.f - zp) * np + zp * xi;
            rowv = Cc + Pp;
            ycol[(long)i * OUTD + D] = rowv;
        }
        {
            const float pr = __shfl_xor(rowv, 1);
            const unsigned int pairu32 = packh2(rowv, pr);
            if (tid < swk && !(tid & 1)) {
                __hip_atomic_store(&tb32[(long)i * (MSG_U64 * 2) + 38 * k + (tid >> 1)], pairu32,
                                   __ATOMIC_RELAXED, __HIP_MEMORY_SCOPE_AGENT);
            }
        }
        float bv = (tid < swk) ? rowv * wkD : 0.f;
        #pragma unroll
        for (int off = 32; off; off >>= 1) bv += __shfl_xor(bv, off);
        if (lane == 0) red[wid] = bv;
        __syncthreads();   // B6: drains mailbox stores (vmcnt 0 at barrier)

        if (tid == 0) {
            const float bsum = red[0] + red[1];
            unsigned int bbits;
            __builtin_memcpy(&bbits, &bsum, 4);
            const unsigned long long pkt =
                ((unsigned long long)bbits << 32) | (unsigned int)(i + 1);
            __hip_atomic_store(&tbu64[(long)i * MSG_U64 + 76 + k], pkt,
                               __ATOMIC_RELAXED, __HIP_MEMORY_SCOPE_AGENT);
        }
    }
}

extern "C" void kernel_launch(void* const* d_in, const int* in_sizes, int n_in,
                              void* d_out, int out_size, void* d_ws, size_t ws_size,
                              hipStream_t stream) {
    (void)in_sizes; (void)n_in; (void)out_size; (void)ws_size;
    const float* features = (const float*)d_in[0];
    const float* fc1_w    = (const float*)d_in[1];
    const float* fc1_b    = (const float*)d_in[2];
    const float* gat_w    = (const float*)d_in[3];
    const float* gc_wih   = (const float*)d_in[5];
    const float* gc_whh   = (const float*)d_in[6];
    const float* gc_bih   = (const float*)d_in[7];
    const float* gc_bhh   = (const float*)d_in[8];
    const float* gp_wih   = (const float*)d_in[9];
    const float* gp_whh   = (const float*)d_in[10];
    const float* gp_bih   = (const float*)d_in[11];
    const float* gp_bhh   = (const float*)d_in[12];
    const int*   adj      = (const int*)d_in[13];
    float* out = (float*)d_out;

    unsigned long long* TB = (unsigned long long*)d_ws;            // 2*64*128*80 u64
    float* GIC = (float*)(TB + 2L * B_ * NB * MSG_U64);            // 64*128*900 f32
    float* GHP = GIC + (long)B_ * NB * G3;
    unsigned int* PK2  = (unsigned int*)(GHP + (long)B_ * NB * G3); // 2*150*1800
    unsigned int* APK2 = PK2 + 2 * 150 * PK_STRIDE;                 // 8192*160
    unsigned int* BPKF = APK2 + 8192L * 160;                        // 320*512
    unsigned int* BPKL = BPKF + 320L * 512;                         // 4*960*160
    unsigned int* APK1 = (unsigned int*)GIC;                        // alias: 8192*512 <= GIC size

    hipFuncSetAttribute(reinterpret_cast<const void*>(scan7),
                        hipFuncAttributeMaxDynamicSharedMemorySize, 80000);
    hipMemsetAsync(TB, 0, 2L * B_ * NB * MSG_U64 * sizeof(unsigned long long), stream);

    copy_feat<<<dim3((B_ * NB * E_) / 1024), 256, 0, stream>>>(features, out);
    pack2<<<dim3((2 * 150 * PK_STRIDE + 255) / 256), 256, 0, stream>>>(gc_whh, gp_wih, PK2);

    // pack GEMM inputs
    pack_af<<<dim3(8192 * 512 / 256), 256, 0, stream>>>(features, APK1);
    pack_bf<<<dim3(320 * 512 / 256), 256, 0, stream>>>(fc1_w, BPKF);
    pack_bw<<<dim3(960 * 160 / 256), 256, 0, stream>>>(gc_wih,               BPKL + 0L * 153600);
    pack_bw<<<dim3(960 * 160 / 256), 256, 0, stream>>>(gp_whh,               BPKL + 1L * 153600);
    pack_bw<<<dim3(960 * 160 / 256), 256, 0, stream>>>(gc_wih + G3 * DH,     BPKL + 2L * 153600);
    pack_bw<<<dim3(960 * 160 / 256), 256, 0, stream>>>(gp_whh + G3 * DH,     BPKL + 3L * 153600);

    // H0 = relu(features @ fc1_w + b) -> out cols [0,300)
    gemm_h16<1><<<dim3(5, 64), 256, 0, stream>>>(APK1, 512, BPKF, 512, fc1_b, out, OUTD, DH, 512);

    for (int l = 0; l < 2; ++l) {
        pack_ah<<<dim3(8192 * 160 / 256), 256, 0, stream>>>(out + l * DH, APK2);
        gemm_h16<0><<<dim3(15, 64), 256, 0, stream>>>(
            APK2, 160, BPKL + (2L * l) * 153600, 160, gc_bih + l * G3, GIC, G3, G3, 160);
        gemm_h16<0><<<dim3(15, 64), 256, 0, stream>>>(
            APK2, 160, BPKL + (2L * l + 1) * 153600, 160, gp_bhh + l * G3, GHP, G3, G3, 160);
        scan7<<<dim3(SLICES * B_), 512, 77824, stream>>>(
            out, GIC, GHP, PK2 + (long)l * 150 * PK_STRIDE,
            gc_bhh + l * G3, gp_bih + l * G3, adj,
            gat_w + l * 2 * DH + DH,
            TB + (long)l * B_ * NB * MSG_U64, l);
    }
}